// Round 6
// baseline (253.634 us; speedup 1.0000x reference)
//
#include <hip/hip_runtime.h>
#include <stdint.h>

#define B_SZ   4096
#define OBS    512
#define T_TASKS 10
#define E_EXP  8
#define W_DIM  1024
#define H_OUT  12
#define XROW   522      // OBS + T
#define NTOT   8192     // E*W

using f32x4  = __attribute__((ext_vector_type(4))) float;
using bf16x8 = __attribute__((ext_vector_type(8))) short;

__device__ __forceinline__ unsigned short f2bf(float f) {
  union { float f; unsigned u; } x; x.f = f;
  unsigned r = x.u + 0x7FFF + ((x.u >> 16) & 1);   // RNE
  return (unsigned short)(r >> 16);
}
__device__ __forceinline__ float bf2f(unsigned short h) {
  union { unsigned u; float f; } x; x.u = ((unsigned)h) << 16;
  return x.f;
}

__device__ __forceinline__ void gload_lds16(const void* g, void* l) {
  __builtin_amdgcn_global_load_lds(
      (const __attribute__((address_space(1))) void*)g,
      (__attribute__((address_space(3))) void*)l,
      16, 0, 0);
}

#define SCHED0  __builtin_amdgcn_sched_barrier(0)
#define VMCNT6  do { asm volatile("s_waitcnt vmcnt(6)" ::: "memory"); SCHED0; } while (0)
#define LGKM0   do { asm volatile("s_waitcnt lgkmcnt(0)" ::: "memory"); SCHED0; } while (0)
#define BARRIER do { SCHED0; asm volatile("s_barrier" ::: "memory"); SCHED0; } while (0)

// ---------------- prep kernels ----------------

__global__ void k_obs_bf16(const float* __restrict__ x, unsigned short* __restrict__ obsB) {
  int i = blockIdx.x * 256 + threadIdx.x;          // over B*OBS, exact grid
  int b = i >> 9, c = i & 511;
  obsB[i] = f2bf(x[(size_t)b * XROW + c]);
}

// W [e][K][1024] f32  ->  Wt [e][1024][K] bf16
__global__ void k_wt(const float* __restrict__ Wsrc, unsigned short* __restrict__ Wt, int K) {
  __shared__ float tile[32][33];
  int e  = blockIdx.z;
  int n0 = blockIdx.x * 32, k0 = blockIdx.y * 32;
  const float* Ws = Wsrc + (size_t)e * K * W_DIM;
  unsigned short* Wd = Wt + (size_t)e * W_DIM * K;
  int tx = threadIdx.x & 31, ty = threadIdx.x >> 5;   // ty 0..7
#pragma unroll
  for (int r = 0; r < 4; ++r)
    tile[ty + r * 8][tx] = Ws[(size_t)(k0 + ty + r * 8) * W_DIM + n0 + tx];
  __syncthreads();
#pragma unroll
  for (int r = 0; r < 4; ++r)
    Wd[(size_t)(n0 + ty + r * 8) * K + k0 + tx] = f2bf(tile[tx][ty + r * 8]);
}

// ---------------- 256x256 GEMM, 4-phase/K-tile, 1 vmcnt/tile, deep prefetch ----------------
// 512 thr = 8 waves (2M x 4N). BK=64, dbuf LDS 128 KB.
// Frame per phase: [head ds_reads] [stage 1 half] BARRIER lgkm(0) MFMA [Q3: vmcnt(6)] BARRIER.
// Cross-wave safety: every half read in tile t was retired by vmcnt(6) at Q3(t-1)
// (or the prologue vmcnt) FOLLOWED BY a barrier -> globally resident in LDS.
// Stage schedule (7 halves in flight steady-state, 14 loads; vmcnt(6) leaves 3 halves):
//   prologue: A0(0) B0(0) B1(0) A1(0) A0(1) B0(1) B1(1)
//   Q0(t): A1(t+1)->nbuf   Q1(t): A0(t+2)->buf   Q2(t): B0(t+2)->buf   Q3(t): B1(t+2)->buf
// WAR: each slot overwrite issues >=1 barrier after the slot's readers' lgkm(0).
// Reads: Q0 af<-A0(t)[8]+bf0<-B0(t)[4]; Q1 bf1<-B1(t)[4]; Q2 af<-A1(t)[8]; Q3 none.

template <bool RELU>
__global__ __launch_bounds__(512, 2) void k_gemm256(
    const unsigned short* __restrict__ A, int lda, int aExpStride,
    const unsigned short* __restrict__ Bt, int K,
    const float* __restrict__ bias,
    unsigned short* __restrict__ C)
{
  extern __shared__ char lds[];
  const int tid  = threadIdx.x;
  const int lane = tid & 63, wid = tid >> 6;
  const int wm = wid >> 2, wn = wid & 3;
  const int rlo = lane & 15, kg = lane >> 4;

  // bijective XCD swizzle: 512 blocks -> 8 XCDs x (8 mblk x 8 nblk)
  int bid = blockIdx.x;
  int xcd = bid & 7, loc = bid >> 3;
  int mblk = ((xcd & 1) << 3) | (loc & 7);
  int nblk = ((xcd >> 1) << 3) | (loc >> 3);
  int m0 = mblk * 256, n0g = nblk * 256;
  int e = n0g >> 10, n0e = n0g & 1023;

  const unsigned short* Ab = A + (size_t)e * aExpStride;
  const unsigned short* Bb = Bt + ((size_t)e * 1024 + n0e) * (size_t)K;

  // staging coords: half-tile = 128 rows x 8 chunks(16B) = 1024 chunks; 2/thread
  const int idx0 = tid, idx1 = 512 + tid;
  const int r0 = idx0 >> 3, p0 = idx0 & 7, c0 = p0 ^ (r0 & 7);  // inverse-swz source
  const int r1 = idx1 >> 3, p1 = idx1 & 7, c1 = p1 ^ (r1 & 7);

  const int NT = K >> 6;
  const size_t ldaz = (size_t)lda, ldkz = (size_t)K;

  auto stageA = [&](int buf, int h, int kt) {
    const unsigned short* g0 = Ab + (size_t)(m0 + h * 128 + r0) * ldaz + kt * 64 + c0 * 8;
    const unsigned short* g1 = Ab + (size_t)(m0 + h * 128 + r1) * ldaz + kt * 64 + c1 * 8;
    char* l = lds + buf * 65536 + h * 16384;
    gload_lds16(g0, l + idx0 * 16);
    gload_lds16(g1, l + idx1 * 16);
  };
  auto stageB = [&](int buf, int h, int kt) {
    const unsigned short* g0 = Bb + (size_t)(h * 128 + r0) * ldkz + kt * 64 + c0 * 8;
    const unsigned short* g1 = Bb + (size_t)(h * 128 + r1) * ldkz + kt * 64 + c1 * 8;
    char* l = lds + buf * 65536 + 32768 + h * 16384;
    gload_lds16(g0, l + idx0 * 16);
    gload_lds16(g1, l + idx1 * 16);
  };
  auto rdA = [&](int buf, int mh, int mi, int ks) -> bf16x8 {
    int r = mi * 32 + wm * 16 + rlo;
    int p = (ks * 4 + kg) ^ (r & 7);               // swizzled read
    return *(const bf16x8*)(lds + buf * 65536 + mh * 16384 + r * 128 + p * 16);
  };
  auto rdB = [&](int buf, int nh, int ni, int ks) -> bf16x8 {
    int r = ni * 64 + wn * 16 + rlo;
    int p = (ks * 4 + kg) ^ (r & 7);
    return *(const bf16x8*)(lds + buf * 65536 + 32768 + nh * 16384 + r * 128 + p * 16);
  };

  f32x4 acc[8][4];
#pragma unroll
  for (int i = 0; i < 8; ++i)
#pragma unroll
    for (int j = 0; j < 4; ++j) acc[i][j] = f32x4{0.f, 0.f, 0.f, 0.f};

  bf16x8 af[8], bf0[4], bf1[4];

  // prologue: 7 halves (14 loads); vmcnt(6) retires tile-0's 4 halves; barrier -> safe to read
  {
    int t1 = NT > 1 ? 1 : 0;
    stageA(0, 0, 0); stageB(0, 0, 0); stageB(0, 1, 0); stageA(0, 1, 0);
    stageA(1, 0, t1); stageB(1, 0, t1); stageB(1, 1, t1);
    VMCNT6;
    BARRIER;
  }

  for (int t = 0; t < NT; ++t) {
    int buf = t & 1, nbuf = buf ^ 1;
    int tn  = (t + 1 < NT) ? t + 1 : NT - 1;       // clamped: counts (and vmcnt math) exact
    int tn2 = (t + 2 < NT) ? t + 2 : NT - 1;

    // ---- Q0: read af<-A0(t), bf0<-B0(t); stage A1(t+1); MFMA af(h0) x bf0 ----
#pragma unroll
    for (int mi = 0; mi < 4; ++mi)
#pragma unroll
      for (int ks = 0; ks < 2; ++ks) af[mi * 2 + ks] = rdA(buf, 0, mi, ks);
#pragma unroll
    for (int ni = 0; ni < 2; ++ni)
#pragma unroll
      for (int ks = 0; ks < 2; ++ks) bf0[ni * 2 + ks] = rdB(buf, 0, ni, ks);
    stageA(nbuf, 1, tn);
    BARRIER;
    LGKM0;
    __builtin_amdgcn_s_setprio(1);
#pragma unroll
    for (int ks = 0; ks < 2; ++ks)
#pragma unroll
      for (int mi = 0; mi < 4; ++mi)
#pragma unroll
        for (int ni = 0; ni < 2; ++ni)
          acc[mi][ni] = __builtin_amdgcn_mfma_f32_16x16x32_bf16(af[mi * 2 + ks], bf0[ni * 2 + ks], acc[mi][ni], 0, 0, 0);
    __builtin_amdgcn_s_setprio(0);
    BARRIER;

    // ---- Q1: read bf1<-B1(t); stage A0(t+2); MFMA af(h0) x bf1 ----
#pragma unroll
    for (int ni = 0; ni < 2; ++ni)
#pragma unroll
      for (int ks = 0; ks < 2; ++ks) bf1[ni * 2 + ks] = rdB(buf, 1, ni, ks);
    stageA(buf, 0, tn2);
    BARRIER;
    LGKM0;
    __builtin_amdgcn_s_setprio(1);
#pragma unroll
    for (int ks = 0; ks < 2; ++ks)
#pragma unroll
      for (int mi = 0; mi < 4; ++mi)
#pragma unroll
        for (int ni = 0; ni < 2; ++ni)
          acc[mi][2 + ni] = __builtin_amdgcn_mfma_f32_16x16x32_bf16(af[mi * 2 + ks], bf1[ni * 2 + ks], acc[mi][2 + ni], 0, 0, 0);
    __builtin_amdgcn_s_setprio(0);
    BARRIER;

    // ---- Q2: read af<-A1(t); stage B0(t+2); MFMA af(h1) x bf1 ----
#pragma unroll
    for (int mi = 0; mi < 4; ++mi)
#pragma unroll
      for (int ks = 0; ks < 2; ++ks) af[mi * 2 + ks] = rdA(buf, 1, mi, ks);
    stageB(buf, 0, tn2);
    BARRIER;
    LGKM0;
    __builtin_amdgcn_s_setprio(1);
#pragma unroll
    for (int ks = 0; ks < 2; ++ks)
#pragma unroll
      for (int mi = 0; mi < 4; ++mi)
#pragma unroll
        for (int ni = 0; ni < 2; ++ni)
          acc[4 + mi][2 + ni] = __builtin_amdgcn_mfma_f32_16x16x32_bf16(af[mi * 2 + ks], bf1[ni * 2 + ks], acc[4 + mi][2 + ni], 0, 0, 0);
    __builtin_amdgcn_s_setprio(0);
    BARRIER;

    // ---- Q3: stage B1(t+2); MFMA af(h1) x bf0; vmcnt(6) retires tile t+1's 4 halves ----
    stageB(buf, 1, tn2);
    BARRIER;
    __builtin_amdgcn_s_setprio(1);
#pragma unroll
    for (int ks = 0; ks < 2; ++ks)
#pragma unroll
      for (int mi = 0; mi < 4; ++mi)
#pragma unroll
        for (int ni = 0; ni < 2; ++ni)
          acc[4 + mi][ni] = __builtin_amdgcn_mfma_f32_16x16x32_bf16(af[mi * 2 + ks], bf0[ni * 2 + ks], acc[4 + mi][ni], 0, 0, 0);
    __builtin_amdgcn_s_setprio(0);
    VMCNT6;
    BARRIER;
  }
  asm volatile("s_waitcnt vmcnt(0)" ::: "memory");
  SCHED0;

  // epilogue: bias (+ReLU) + bf16 store
  int rbase = kg * 4;
#pragma unroll
  for (int fi = 0; fi < 8; ++fi) {
    int mh = fi >> 2, mi = fi & 3;
    int rowg = m0 + mh * 128 + mi * 32 + wm * 16 + rbase;
#pragma unroll
    for (int fj = 0; fj < 4; ++fj) {
      int nh = fj >> 1, ni = fj & 1;
      int colr = nh * 128 + ni * 64 + wn * 16 + rlo;
      int colg = n0g + colr;
      float bv = bias[e * W_DIM + n0e + colr];
#pragma unroll
      for (int j = 0; j < 4; ++j) {
        float v = acc[fi][fj][j] + bv;
        if (RELU) v = fmaxf(v, 0.0f);
        C[(size_t)(rowg + j) * NTOT + colg] = f2bf(v);
      }
    }
  }
}

// ---------------- Gram-Schmidt + feat + head: one WAVE per batch row ----------------

__device__ __forceinline__ float wred(float s) {
#pragma unroll
  for (int m = 32; m; m >>= 1) s += __shfl_xor(s, m, 64);
  return s;
}

__global__ __launch_bounds__(256, 1) void k_gs_wave(
    const unsigned short* __restrict__ eo,   // [B][8192] bf16
    const float* __restrict__ x,
    const float* __restrict__ te_W,          // [10][8]
    const float* __restrict__ head_W,        // [10][1024][12]
    const float* __restrict__ head_b,        // [10][12]
    float* __restrict__ out)                 // [B][12]
{
  int wid = threadIdx.x >> 6, lane = threadIdx.x & 63;
  int b = blockIdx.x * 4 + wid;

  float v[8][16];
  const unsigned short* row = eo + (size_t)b * NTOT;
#pragma unroll
  for (int i = 0; i < E_EXP; ++i) {
#pragma unroll
    for (int half = 0; half < 2; ++half) {
      bf16x8 t = *(const bf16x8*)&row[i * 1024 + half * 512 + lane * 8];
#pragma unroll
      for (int k = 0; k < 8; ++k) v[i][half * 8 + k] = bf2f((unsigned short)t[k]);
    }
  }

  int idx = 0; float mv = x[(size_t)b * XROW + OBS];
#pragma unroll
  for (int t = 1; t < T_TASKS; ++t) {
    float val = x[(size_t)b * XROW + OBS + t];
    if (val > mv) { mv = val; idx = t; }
  }

  float cf[7];
#pragma unroll
  for (int i = 0; i < E_EXP; ++i) {
#pragma unroll
    for (int j = 0; j < 7; ++j) {
      if (j < i) {
        float p = 0.f;
#pragma unroll
        for (int c = 0; c < 16; ++c) p += v[i][c] * v[j][c];
        cf[j] = wred(p);
      }
    }
#pragma unroll
    for (int c = 0; c < 16; ++c) {
      float w = v[i][c];
#pragma unroll
      for (int j = 0; j < 7; ++j)
        if (j < i) w -= cf[j] * v[j][c];
      v[i][c] = w;
    }
    float p = 0.f;
#pragma unroll
    for (int c = 0; c < 16; ++c) p += v[i][c] * v[i][c];
    float nrm = sqrtf(wred(p));
    float s = 1.0f / (nrm + 1e-8f);
#pragma unroll
    for (int c = 0; c < 16; ++c) v[i][c] *= s;
  }

  float te[E_EXP];
#pragma unroll
  for (int e2 = 0; e2 < E_EXP; ++e2) te[e2] = te_W[idx * E_EXP + e2];

  float ph[H_OUT];
#pragma unroll
  for (int h = 0; h < H_OUT; ++h) ph[h] = 0.f;
  const float* hw = head_W + (size_t)idx * W_DIM * H_OUT;

#pragma unroll
  for (int half = 0; half < 2; ++half) {
#pragma unroll
    for (int k = 0; k < 8; ++k) {
      int c = half * 512 + lane * 8 + k;
      float f = 0.f;
#pragma unroll
      for (int e2 = 0; e2 < E_EXP; ++e2) f += te[e2] * v[e2][half * 8 + k];
      f = tanhf(f);
      const float* hwc = hw + (size_t)c * H_OUT;
#pragma unroll
      for (int h = 0; h < H_OUT; ++h) ph[h] += f * hwc[h];
    }
  }

#pragma unroll
  for (int h = 0; h < H_OUT; ++h) ph[h] = wred(ph[h]);
  if (lane == 0) {
#pragma unroll
    for (int h = 0; h < H_OUT; ++h)
      out[(size_t)b * H_OUT + h] = ph[h] + head_b[idx * H_OUT + h];
  }
}

// ---------------- launch ----------------

extern "C" void kernel_launch(void* const* d_in, const int* in_sizes, int n_in,
                              void* d_out, int out_size, void* d_ws, size_t ws_size,
                              hipStream_t stream) {
  const float* x     = (const float*)d_in[0];
  const float* te_W  = (const float*)d_in[1];
  const float* W0    = (const float*)d_in[2];
  const float* b0    = (const float*)d_in[3];
  const float* W1    = (const float*)d_in[4];
  const float* b1    = (const float*)d_in[5];
  const float* W2    = (const float*)d_in[6];
  const float* b2    = (const float*)d_in[7];
  const float* headW = (const float*)d_in[8];
  const float* headb = (const float*)d_in[9];
  float* out = (float*)d_out;

  char* ws = (char*)d_ws;
  size_t off = 0;
  auto alloc = [&](size_t bytes) {
    void* p = ws + off;
    off += (bytes + 255) & ~(size_t)255;
    return p;
  };
  unsigned short* obsB = (unsigned short*)alloc((size_t)B_SZ * OBS * 2);
  unsigned short* W0t  = (unsigned short*)alloc((size_t)8 * 1024 * 512 * 2);
  unsigned short* W1t  = (unsigned short*)alloc((size_t)8 * 1024 * 1024 * 2);
  unsigned short* W2t  = (unsigned short*)alloc((size_t)8 * 1024 * 1024 * 2);
  unsigned short* h0   = (unsigned short*)alloc((size_t)B_SZ * NTOT * 2);
  unsigned short* h1   = (unsigned short*)alloc((size_t)B_SZ * NTOT * 2);
  unsigned short* eo   = (unsigned short*)alloc((size_t)B_SZ * NTOT * 2);
  (void)ws_size; (void)in_sizes; (void)n_in; (void)out_size;

  k_obs_bf16<<<(B_SZ * OBS) / 256, 256, 0, stream>>>(x, obsB);
  k_wt<<<dim3(32, 16, 8), 256, 0, stream>>>(W0, W0t, 512);
  k_wt<<<dim3(32, 32, 8), 256, 0, stream>>>(W1, W1t, 1024);
  k_wt<<<dim3(32, 32, 8), 256, 0, stream>>>(W2, W2t, 1024);

  k_gemm256<true ><<<512, 512, 131072, stream>>>(obsB, 512,  0,    W0t, 512,  b0, h0);
  k_gemm256<true ><<<512, 512, 131072, stream>>>(h0,   NTOT, 1024, W1t, 1024, b1, h1);
  k_gemm256<false><<<512, 512, 131072, stream>>>(h1,   NTOT, 1024, W2t, 1024, b2, eo);

  k_gs_wave<<<B_SZ / 4, 256, 0, stream>>>(eo, x, te_W, headW, headb, out);
}

// Round 7
// 241.443 us; speedup vs baseline: 1.0505x; 1.0505x over previous
//
#include <hip/hip_runtime.h>
#include <stdint.h>

#define B_SZ   4096
#define OBS    512
#define T_TASKS 10
#define E_EXP  8
#define W_DIM  1024
#define H_OUT  12
#define XROW   522      // OBS + T
#define NTOT   8192     // E*W

using f32x4  = __attribute__((ext_vector_type(4))) float;
using bf16x8 = __attribute__((ext_vector_type(8))) short;

__device__ __forceinline__ unsigned short f2bf(float f) {
  union { float f; unsigned u; } x; x.f = f;
  unsigned r = x.u + 0x7FFF + ((x.u >> 16) & 1);   // RNE
  return (unsigned short)(r >> 16);
}
__device__ __forceinline__ float bf2f(unsigned short h) {
  union { unsigned u; float f; } x; x.u = ((unsigned)h) << 16;
  return x.f;
}

__device__ __forceinline__ void gload_lds16(const void* g, void* l) {
  __builtin_amdgcn_global_load_lds(
      (const __attribute__((address_space(1))) void*)g,
      (__attribute__((address_space(3))) void*)l,
      16, 0, 0);
}

#define SCHED0  __builtin_amdgcn_sched_barrier(0)
#define VMCNT8  do { asm volatile("s_waitcnt vmcnt(8)" ::: "memory"); SCHED0; } while (0)
#define LGKM0   do { asm volatile("s_waitcnt lgkmcnt(0)" ::: "memory"); SCHED0; } while (0)
#define BARRIER do { SCHED0; asm volatile("s_barrier" ::: "memory"); SCHED0; } while (0)

// ---------------- prep kernels ----------------

__global__ void k_obs_bf16(const float* __restrict__ x, unsigned short* __restrict__ obsB) {
  int i = blockIdx.x * 256 + threadIdx.x;          // over B*OBS, exact grid
  int b = i >> 9, c = i & 511;
  obsB[i] = f2bf(x[(size_t)b * XROW + c]);
}

// W [e][K][1024] f32  ->  Wt [e][1024][K] bf16
__global__ void k_wt(const float* __restrict__ Wsrc, unsigned short* __restrict__ Wt, int K) {
  __shared__ float tile[32][33];
  int e  = blockIdx.z;
  int n0 = blockIdx.x * 32, k0 = blockIdx.y * 32;
  const float* Ws = Wsrc + (size_t)e * K * W_DIM;
  unsigned short* Wd = Wt + (size_t)e * W_DIM * K;
  int tx = threadIdx.x & 31, ty = threadIdx.x >> 5;   // ty 0..7
#pragma unroll
  for (int r = 0; r < 4; ++r)
    tile[ty + r * 8][tx] = Ws[(size_t)(k0 + ty + r * 8) * W_DIM + n0 + tx];
  __syncthreads();
#pragma unroll
  for (int r = 0; r < 4; ++r)
    Wd[(size_t)(n0 + ty + r * 8) * K + k0 + tx] = f2bf(tile[tx][ty + r * 8]);
}

// ---------------- 256x256 GEMM, 4 phases/K-tile, ONE barrier per phase ----------------
// 512 thr = 8 waves (2M x 4N). BK=64, dbuf LDS 128 KB.
// Frame: { ds_reads ; stage ; [vmcnt(8)] ; BARRIER ; lgkm(0) ; setprio ; 16 MFMA ; setprio }
// -> no post-MFMA barrier: next phase's ds_reads overlap sibling waves' MFMA.
// Issue order (steady): ... A0(t),B0(t) | B1(t) | A1(t) | A0(t+1),B0(t+1) | B1(t+1) ...
// vmcnt(8)@Q1(t) retires A1(t) (read Q2(t), after barrier(Q1)).
// vmcnt(8)@Q3(t) retires A0/B0/B1(t+1) (read Q0/Q1(t+1), after barrier(Q3)).
// WAR (all barrier-guaranteed): A1(t+1)@Q0(t) after barrier(Q3,t-1) [readers drained at
// lgkm0(Q2,t-1) < their barrier(Q3) arrival]; A0/B0(t+2)@Q2(t) after barrier(Q1,t)
// [readers' lgkm0(Q0,t) < their barrier(Q1) arrival]; B1(t+2)@Q3(t) after barrier(Q2,t).

template <bool RELU>
__global__ __launch_bounds__(512, 2) void k_gemm256(
    const unsigned short* __restrict__ A, int lda, int aExpStride,
    const unsigned short* __restrict__ Bt, int K,
    const float* __restrict__ bias,
    unsigned short* __restrict__ C)
{
  extern __shared__ char lds[];
  const int tid  = threadIdx.x;
  const int lane = tid & 63, wid = tid >> 6;
  const int wm = wid >> 2, wn = wid & 3;
  const int rlo = lane & 15, kg = lane >> 4;

  // bijective XCD swizzle: 512 blocks -> 8 XCDs x (8 mblk x 8 nblk)
  int bid = blockIdx.x;
  int xcd = bid & 7, loc = bid >> 3;
  int mblk = ((xcd & 1) << 3) | (loc & 7);
  int nblk = ((xcd >> 1) << 3) | (loc >> 3);
  int m0 = mblk * 256, n0g = nblk * 256;
  int e = n0g >> 10, n0e = n0g & 1023;

  const unsigned short* Ab = A + (size_t)e * aExpStride;
  const unsigned short* Bb = Bt + ((size_t)e * 1024 + n0e) * (size_t)K;

  // staging coords: half-tile = 128 rows x 8 chunks(16B) = 1024 chunks; 2/thread
  const int idx0 = tid, idx1 = 512 + tid;
  const int r0 = idx0 >> 3, p0 = idx0 & 7, c0 = p0 ^ (r0 & 7);  // inverse-swz source
  const int r1 = idx1 >> 3, p1 = idx1 & 7, c1 = p1 ^ (r1 & 7);

  const int NT = K >> 6;
  const size_t ldaz = (size_t)lda, ldkz = (size_t)K;

  auto stageA = [&](int buf, int h, int kt) {
    const unsigned short* g0 = Ab + (size_t)(m0 + h * 128 + r0) * ldaz + kt * 64 + c0 * 8;
    const unsigned short* g1 = Ab + (size_t)(m0 + h * 128 + r1) * ldaz + kt * 64 + c1 * 8;
    char* l = lds + buf * 65536 + h * 16384;
    gload_lds16(g0, l + idx0 * 16);
    gload_lds16(g1, l + idx1 * 16);
  };
  auto stageB = [&](int buf, int h, int kt) {
    const unsigned short* g0 = Bb + (size_t)(h * 128 + r0) * ldkz + kt * 64 + c0 * 8;
    const unsigned short* g1 = Bb + (size_t)(h * 128 + r1) * ldkz + kt * 64 + c1 * 8;
    char* l = lds + buf * 65536 + 32768 + h * 16384;
    gload_lds16(g0, l + idx0 * 16);
    gload_lds16(g1, l + idx1 * 16);
  };
  auto rdA = [&](int buf, int mh, int mi, int ks) -> bf16x8 {
    int r = mi * 32 + wm * 16 + rlo;
    int p = (ks * 4 + kg) ^ (r & 7);               // swizzled read
    return *(const bf16x8*)(lds + buf * 65536 + mh * 16384 + r * 128 + p * 16);
  };
  auto rdB = [&](int buf, int nh, int ni, int ks) -> bf16x8 {
    int r = ni * 64 + wn * 16 + rlo;
    int p = (ks * 4 + kg) ^ (r & 7);
    return *(const bf16x8*)(lds + buf * 65536 + 32768 + nh * 16384 + r * 128 + p * 16);
  };

  f32x4 acc[8][4];
#pragma unroll
  for (int i = 0; i < 8; ++i)
#pragma unroll
    for (int j = 0; j < 4; ++j) acc[i][j] = f32x4{0.f, 0.f, 0.f, 0.f};

  bf16x8 af[8], bf0[4], bf1[4];

  // prologue: 7 halves, 14 loads, in steady-state FIFO order; vmcnt(8) retires
  // A0(0),B0(0),B1(0) (first 6) -> barrier -> Q0(0) reads safe.
  {
    int t1 = NT > 1 ? 1 : 0;
    stageA(0, 0, 0); stageB(0, 0, 0); stageB(0, 1, 0);
    stageA(0, 1, 0);
    stageA(1, 0, t1); stageB(1, 0, t1); stageB(1, 1, t1);
    VMCNT8;
    BARRIER;
  }

  for (int t = 0; t < NT; ++t) {
    int buf = t & 1, nbuf = buf ^ 1;
    int tn  = (t + 1 < NT) ? t + 1 : NT - 1;       // clamped: counts stay exact;
    int tn2 = (t + 2 < NT) ? t + 2 : NT - 1;       // clamped data lands in dead slots

    // ---- Q0: reads af<-A0(t)[8], bf0<-B0(t)[4]; stage A1(t+1)->nbuf ----
#pragma unroll
    for (int mi = 0; mi < 4; ++mi)
#pragma unroll
      for (int ks = 0; ks < 2; ++ks) af[mi * 2 + ks] = rdA(buf, 0, mi, ks);
#pragma unroll
    for (int ni = 0; ni < 2; ++ni)
#pragma unroll
      for (int ks = 0; ks < 2; ++ks) bf0[ni * 2 + ks] = rdB(buf, 0, ni, ks);
    stageA(nbuf, 1, tn);
    BARRIER;
    LGKM0;
    __builtin_amdgcn_s_setprio(1);
#pragma unroll
    for (int ks = 0; ks < 2; ++ks)
#pragma unroll
      for (int mi = 0; mi < 4; ++mi)
#pragma unroll
        for (int ni = 0; ni < 2; ++ni)
          acc[mi][ni] = __builtin_amdgcn_mfma_f32_16x16x32_bf16(af[mi * 2 + ks], bf0[ni * 2 + ks], acc[mi][ni], 0, 0, 0);
    __builtin_amdgcn_s_setprio(0);

    // ---- Q1: reads bf1<-B1(t)[4]; vmcnt(8) retires A1(t) ----
#pragma unroll
    for (int ni = 0; ni < 2; ++ni)
#pragma unroll
      for (int ks = 0; ks < 2; ++ks) bf1[ni * 2 + ks] = rdB(buf, 1, ni, ks);
    VMCNT8;
    BARRIER;
    LGKM0;
    __builtin_amdgcn_s_setprio(1);
#pragma unroll
    for (int ks = 0; ks < 2; ++ks)
#pragma unroll
      for (int mi = 0; mi < 4; ++mi)
#pragma unroll
        for (int ni = 0; ni < 2; ++ni)
          acc[mi][2 + ni] = __builtin_amdgcn_mfma_f32_16x16x32_bf16(af[mi * 2 + ks], bf1[ni * 2 + ks], acc[mi][2 + ni], 0, 0, 0);
    __builtin_amdgcn_s_setprio(0);

    // ---- Q2: reads af<-A1(t)[8]; stage A0(t+2)->buf, B0(t+2)->buf ----
#pragma unroll
    for (int mi = 0; mi < 4; ++mi)
#pragma unroll
      for (int ks = 0; ks < 2; ++ks) af[mi * 2 + ks] = rdA(buf, 1, mi, ks);
    stageA(buf, 0, tn2);
    stageB(buf, 0, tn2);
    BARRIER;
    LGKM0;
    __builtin_amdgcn_s_setprio(1);
#pragma unroll
    for (int ks = 0; ks < 2; ++ks)
#pragma unroll
      for (int mi = 0; mi < 4; ++mi)
#pragma unroll
        for (int ni = 0; ni < 2; ++ni)
          acc[4 + mi][2 + ni] = __builtin_amdgcn_mfma_f32_16x16x32_bf16(af[mi * 2 + ks], bf1[ni * 2 + ks], acc[4 + mi][2 + ni], 0, 0, 0);
    __builtin_amdgcn_s_setprio(0);

    // ---- Q3: stage B1(t+2)->buf; vmcnt(8) retires A0/B0/B1(t+1); no new reads ----
    stageB(buf, 1, tn2);
    VMCNT8;
    BARRIER;
    __builtin_amdgcn_s_setprio(1);
#pragma unroll
    for (int ks = 0; ks < 2; ++ks)
#pragma unroll
      for (int mi = 0; mi < 4; ++mi)
#pragma unroll
        for (int ni = 0; ni < 2; ++ni)
          acc[4 + mi][ni] = __builtin_amdgcn_mfma_f32_16x16x32_bf16(af[mi * 2 + ks], bf0[ni * 2 + ks], acc[4 + mi][ni], 0, 0, 0);
    __builtin_amdgcn_s_setprio(0);
  }
  asm volatile("s_waitcnt vmcnt(0)" ::: "memory");
  SCHED0;

  // epilogue: bias (+ReLU) + bf16 store
  int rbase = kg * 4;
#pragma unroll
  for (int fi = 0; fi < 8; ++fi) {
    int mh = fi >> 2, mi = fi & 3;
    int rowg = m0 + mh * 128 + mi * 32 + wm * 16 + rbase;
#pragma unroll
    for (int fj = 0; fj < 4; ++fj) {
      int nh = fj >> 1, ni = fj & 1;
      int colr = nh * 128 + ni * 64 + wn * 16 + rlo;
      int colg = n0g + colr;
      float bv = bias[e * W_DIM + n0e + colr];
#pragma unroll
      for (int j = 0; j < 4; ++j) {
        float v = acc[fi][fj][j] + bv;
        if (RELU) v = fmaxf(v, 0.0f);
        C[(size_t)(rowg + j) * NTOT + colg] = f2bf(v);
      }
    }
  }
}

// ---------------- Gram-Schmidt + feat + head: one WAVE per batch row ----------------

__device__ __forceinline__ float wred(float s) {
#pragma unroll
  for (int m = 32; m; m >>= 1) s += __shfl_xor(s, m, 64);
  return s;
}

__global__ __launch_bounds__(256, 1) void k_gs_wave(
    const unsigned short* __restrict__ eo,   // [B][8192] bf16
    const float* __restrict__ x,
    const float* __restrict__ te_W,          // [10][8]
    const float* __restrict__ head_W,        // [10][1024][12]
    const float* __restrict__ head_b,        // [10][12]
    float* __restrict__ out)                 // [B][12]
{
  int wid = threadIdx.x >> 6, lane = threadIdx.x & 63;
  int b = blockIdx.x * 4 + wid;

  float v[8][16];
  const unsigned short* row = eo + (size_t)b * NTOT;
#pragma unroll
  for (int i = 0; i < E_EXP; ++i) {
#pragma unroll
    for (int half = 0; half < 2; ++half) {
      bf16x8 t = *(const bf16x8*)&row[i * 1024 + half * 512 + lane * 8];
#pragma unroll
      for (int k = 0; k < 8; ++k) v[i][half * 8 + k] = bf2f((unsigned short)t[k]);
    }
  }

  int idx = 0; float mv = x[(size_t)b * XROW + OBS];
#pragma unroll
  for (int t = 1; t < T_TASKS; ++t) {
    float val = x[(size_t)b * XROW + OBS + t];
    if (val > mv) { mv = val; idx = t; }
  }

  float cf[7];
#pragma unroll
  for (int i = 0; i < E_EXP; ++i) {
#pragma unroll
    for (int j = 0; j < 7; ++j) {
      if (j < i) {
        float p = 0.f;
#pragma unroll
        for (int c = 0; c < 16; ++c) p += v[i][c] * v[j][c];
        cf[j] = wred(p);
      }
    }
#pragma unroll
    for (int c = 0; c < 16; ++c) {
      float w = v[i][c];
#pragma unroll
      for (int j = 0; j < 7; ++j)
        if (j < i) w -= cf[j] * v[j][c];
      v[i][c] = w;
    }
    float p = 0.f;
#pragma unroll
    for (int c = 0; c < 16; ++c) p += v[i][c] * v[i][c];
    float nrm = sqrtf(wred(p));
    float s = 1.0f / (nrm + 1e-8f);
#pragma unroll
    for (int c = 0; c < 16; ++c) v[i][c] *= s;
  }

  float te[E_EXP];
#pragma unroll
  for (int e2 = 0; e2 < E_EXP; ++e2) te[e2] = te_W[idx * E_EXP + e2];

  float ph[H_OUT];
#pragma unroll
  for (int h = 0; h < H_OUT; ++h) ph[h] = 0.f;
  const float* hw = head_W + (size_t)idx * W_DIM * H_OUT;

#pragma unroll
  for (int half = 0; half < 2; ++half) {
#pragma unroll
    for (int k = 0; k < 8; ++k) {
      int c = half * 512 + lane * 8 + k;
      float f = 0.f;
#pragma unroll
      for (int e2 = 0; e2 < E_EXP; ++e2) f += te[e2] * v[e2][half * 8 + k];
      f = tanhf(f);
      const float* hwc = hw + (size_t)c * H_OUT;
#pragma unroll
      for (int h = 0; h < H_OUT; ++h) ph[h] += f * hwc[h];
    }
  }

#pragma unroll
  for (int h = 0; h < H_OUT; ++h) ph[h] = wred(ph[h]);
  if (lane == 0) {
#pragma unroll
    for (int h = 0; h < H_OUT; ++h)
      out[(size_t)b * H_OUT + h] = ph[h] + head_b[idx * H_OUT + h];
  }
}

// ---------------- launch ----------------

extern "C" void kernel_launch(void* const* d_in, const int* in_sizes, int n_in,
                              void* d_out, int out_size, void* d_ws, size_t ws_size,
                              hipStream_t stream) {
  const float* x     = (const float*)d_in[0];
  const float* te_W  = (const float*)d_in[1];
  const float* W0    = (const float*)d_in[2];
  const float* b0    = (const float*)d_in[3];
  const float* W1    = (const float*)d_in[4];
  const float* b1    = (const float*)d_in[5];
  const float* W2    = (const float*)d_in[6];
  const float* b2    = (const float*)d_in[7];
  const float* headW = (const float*)d_in[8];
  const float* headb = (const float*)d_in[9];
  float* out = (float*)d_out;

  char* ws = (char*)d_ws;
  size_t off = 0;
  auto alloc = [&](size_t bytes) {
    void* p = ws + off;
    off += (bytes + 255) & ~(size_t)255;
    return p;
  };
  unsigned short* obsB = (unsigned short*)alloc((size_t)B_SZ * OBS * 2);
  unsigned short* W0t  = (unsigned short*)alloc((size_t)8 * 1024 * 512 * 2);
  unsigned short* W1t  = (unsigned short*)alloc((size_t)8 * 1024 * 1024 * 2);
  unsigned short* W2t  = (unsigned short*)alloc((size_t)8 * 1024 * 1024 * 2);
  unsigned short* h0   = (unsigned short*)alloc((size_t)B_SZ * NTOT * 2);
  unsigned short* h1   = (unsigned short*)alloc((size_t)B_SZ * NTOT * 2);
  unsigned short* eo   = (unsigned short*)alloc((size_t)B_SZ * NTOT * 2);
  (void)ws_size; (void)in_sizes; (void)n_in; (void)out_size;

  k_obs_bf16<<<(B_SZ * OBS) / 256, 256, 0, stream>>>(x, obsB);
  k_wt<<<dim3(32, 16, 8), 256, 0, stream>>>(W0, W0t, 512);
  k_wt<<<dim3(32, 32, 8), 256, 0, stream>>>(W1, W1t, 1024);
  k_wt<<<dim3(32, 32, 8), 256, 0, stream>>>(W2, W2t, 1024);

  k_gemm256<true ><<<512, 512, 131072, stream>>>(obsB, 512,  0,    W0t, 512,  b0, h0);
  k_gemm256<true ><<<512, 512, 131072, stream>>>(h0,   NTOT, 1024, W1t, 1024, b1, h1);
  k_gemm256<false><<<512, 512, 131072, stream>>>(h1,   NTOT, 1024, W2t, 1024, b2, eo);

  k_gs_wave<<<B_SZ / 4, 256, 0, stream>>>(eo, x, te_W, headW, headb, out);
}